// Round 1
// baseline (565.900 us; speedup 1.0000x reference)
//
#include <hip/hip_runtime.h>
#include <math.h>

#define P_TOT 40000
#define NMAX 32
#define BATCH 4
#define YL 496
#define XL 432
#define CIN 9
#define COUT 64
#define NTRI 45
#define PN_F 1280000.0f

#define MAP_ELEMS (BATCH * YL * XL)          // 857088
#define MAP_BYTES (MAP_ELEMS * 4)            // 3428352
#define STATS_OFF MAP_BYTES                  // 54 floats (reserve 256B)
#define SCALE_OFF (STATS_OFF + 256)
#define SHIFT_OFF (SCALE_OFF + 256)
#define POOLED_OFF (SHIFT_OFF + 256)

// ---------------------------------------------------------------------------
// K0: init map to -1, zero stat accumulators (ws is poisoned 0xAA each call)
// ---------------------------------------------------------------------------
__global__ __launch_bounds__(256) void k_init(int* __restrict__ map,
                                              float* __restrict__ stats) {
    int i = blockIdx.x * 256 + threadIdx.x;
    if (i < MAP_ELEMS) map[i] = -1;
    if (i < 54) stats[i] = 0.0f;
}

// ---------------------------------------------------------------------------
// K1: per-pillar features -> accumulate 9 first moments + 45 second moments
//     (wave shuffle reduce, then atomicAdd). Also scatter pillar id into map.
// ---------------------------------------------------------------------------
__global__ __launch_bounds__(256) void k_stats(const float4* __restrict__ pillars,
                                               const int* __restrict__ coors,
                                               const int* __restrict__ npp,
                                               int* __restrict__ map,
                                               float* __restrict__ stats) {
    int p = blockIdx.x * 256 + threadIdx.x;
    float s1[CIN];
    float s2[NTRI];
#pragma unroll
    for (int i = 0; i < CIN; i++) s1[i] = 0.0f;
#pragma unroll
    for (int i = 0; i < NTRI; i++) s2[i] = 0.0f;

    if (p < P_TOT) {
        int b = coors[p * 3 + 0];
        int xi = coors[p * 3 + 1];
        int yi = coors[p * 3 + 2];
        map[(b * YL + yi) * XL + xi] = p;

        int npts = npp[p];
        float cx = (float)xi * 0.16f + 0.08f;
        float cy = (float)yi * 0.16f + (-39.6f);

        const float4* base = pillars + (size_t)p * NMAX;
        // pass 1: center = sum over ALL 32 points / npts (reference semantics)
        float sx = 0.f, sy = 0.f, sz = 0.f;
        for (int n = 0; n < NMAX; n++) {
            float4 q = base[n];
            sx += q.x; sy += q.y; sz += q.z;
        }
        float fn = (float)npts;
        float mx = sx / fn, my = sy / fn, mz = sz / fn;

        // pass 2: only valid (n < npts) points contribute (masked features = 0)
        for (int n = 0; n < npts; n++) {
            float4 q = base[n];
            float f[CIN];
            f[0] = q.x; f[1] = q.y; f[2] = q.z; f[3] = q.w;
            f[4] = q.x - mx; f[5] = q.y - my; f[6] = q.z - mz;
            f[7] = q.x - cx; f[8] = q.y - cy;
            int k = 0;
#pragma unroll
            for (int a = 0; a < CIN; a++) {
                s1[a] += f[a];
#pragma unroll
                for (int c = a; c < CIN; c++) s2[k++] += f[a] * f[c];
            }
        }
    }

    // wave (64-lane) butterfly reduce, then one atomicAdd per value per wave
#pragma unroll
    for (int i = 0; i < CIN; i++) {
        float v = s1[i];
        for (int off = 1; off < 64; off <<= 1) v += __shfl_xor(v, off, 64);
        s1[i] = v;
    }
#pragma unroll
    for (int i = 0; i < NTRI; i++) {
        float v = s2[i];
        for (int off = 1; off < 64; off <<= 1) v += __shfl_xor(v, off, 64);
        s2[i] = v;
    }
    if ((threadIdx.x & 63) == 0) {
#pragma unroll
        for (int i = 0; i < CIN; i++) atomicAdd(&stats[i], s1[i]);
#pragma unroll
        for (int i = 0; i < NTRI; i++) atomicAdd(&stats[CIN + i], s2[i]);
    }
}

// ---------------------------------------------------------------------------
// K2: derive per-channel BN scale/shift from moment matrix (64 threads)
//     mean_o = W[o].m ; E[x^2]_o = W[o] M W[o]^T ; var = E[x^2] - mean^2
// ---------------------------------------------------------------------------
__global__ void k_finalize(const float* __restrict__ W,
                           const float* __restrict__ gamma,
                           const float* __restrict__ beta,
                           const float* __restrict__ stats,
                           float* __restrict__ scale,
                           float* __restrict__ shift) {
    int o = threadIdx.x;  // 64 threads
    float w[CIN];
#pragma unroll
    for (int c = 0; c < CIN; c++) w[c] = W[o * CIN + c];

    const float invPN = 1.0f / PN_F;
    float mu = 0.0f;
#pragma unroll
    for (int c = 0; c < CIN; c++) mu += w[c] * (stats[c] * invPN);

    float ex2 = 0.0f;
    int k = 0;
#pragma unroll
    for (int a = 0; a < CIN; a++) {
#pragma unroll
        for (int c = a; c < CIN; c++) {
            float Mv = stats[CIN + k] * invPN;
            float t = w[a] * w[c] * Mv;
            ex2 += (a == c) ? t : 2.0f * t;
            k++;
        }
    }
    float var = ex2 - mu * mu;
    float sc = gamma[o] * rsqrtf(var + 1e-3f);
    scale[o] = sc;
    shift[o] = beta[o] - mu * sc;
}

// ---------------------------------------------------------------------------
// K3: pooled[p][o] = relu( max_n ( scale_o * (W[o].f[p][n]) + shift_o ) )
//     wave-per-pillar; features staged in LDS; lane = output channel.
//     Masked columns (f=0) correctly contribute relu(shift_o) to the max.
// ---------------------------------------------------------------------------
__global__ __launch_bounds__(256) void k_pool(const float4* __restrict__ pillars,
                                              const int* __restrict__ coors,
                                              const int* __restrict__ npp,
                                              const float* __restrict__ W,
                                              const float* __restrict__ scale,
                                              const float* __restrict__ shift,
                                              float* __restrict__ pooled) {
    __shared__ float fsh[4][NMAX][CIN];
    int w = threadIdx.x >> 6;
    int lane = threadIdx.x & 63;
    int p = blockIdx.x * 4 + w;
    int n = lane & 31;

    float4 q = pillars[(size_t)p * NMAX + n];
    // sum xyz over the 32 points (both 32-lane halves hold identical copies)
    float sx = q.x, sy = q.y, sz = q.z;
#pragma unroll
    for (int off = 1; off < 32; off <<= 1) {
        sx += __shfl_xor(sx, off, 32);
        sy += __shfl_xor(sy, off, 32);
        sz += __shfl_xor(sz, off, 32);
    }
    int npts = npp[p];
    float fn = (float)npts;
    float mx = sx / fn, my = sy / fn, mz = sz / fn;
    int xi = coors[p * 3 + 1];
    int yi = coors[p * 3 + 2];
    float cx = (float)xi * 0.16f + 0.08f;
    float cy = (float)yi * 0.16f + (-39.6f);

    if (lane < 32) {
        bool valid = (n < npts);
        fsh[w][n][0] = valid ? q.x : 0.0f;
        fsh[w][n][1] = valid ? q.y : 0.0f;
        fsh[w][n][2] = valid ? q.z : 0.0f;
        fsh[w][n][3] = valid ? q.w : 0.0f;
        fsh[w][n][4] = valid ? (q.x - mx) : 0.0f;
        fsh[w][n][5] = valid ? (q.y - my) : 0.0f;
        fsh[w][n][6] = valid ? (q.z - mz) : 0.0f;
        fsh[w][n][7] = valid ? (q.x - cx) : 0.0f;
        fsh[w][n][8] = valid ? (q.y - cy) : 0.0f;
    }
    __syncthreads();

    float wv[CIN];
#pragma unroll
    for (int c = 0; c < CIN; c++) wv[c] = W[lane * CIN + c];
    float sc = scale[lane];
    float sh = shift[lane];

    float m = -INFINITY;
#pragma unroll 4
    for (int nn = 0; nn < NMAX; nn++) {
        float d = 0.0f;
#pragma unroll
        for (int c = 0; c < CIN; c++) d += wv[c] * fsh[w][nn][c];
        m = fmaxf(m, sc * d + sh);
    }
    pooled[(size_t)p * COUT + lane] = fmaxf(m, 0.0f);
}

// ---------------------------------------------------------------------------
// K4: write the whole canvas (B,C,Y,X) coalesced. Thread per (b,y,x4):
//     read int4 map once, loop 64 channels, 4x4 register transpose,
//     float4 stores. Map read traffic 3.4MB, pooled 10MB, writes 219MB.
// ---------------------------------------------------------------------------
__global__ __launch_bounds__(256) void k_scatter(const int* __restrict__ map,
                                                 const float* __restrict__ pooled,
                                                 float* __restrict__ out) {
    int i = blockIdx.x * 256 + threadIdx.x;  // over BATCH*YL*(XL/4) = 214272
    if (i >= BATCH * YL * (XL / 4)) return;
    int x4 = i % (XL / 4);
    int r = i / (XL / 4);
    int y = r % YL;
    int b = r / YL;

    const int4 pid = *(const int4*)(map + (size_t)(b * YL + y) * XL + x4 * 4);
    size_t obase = ((size_t)(b * COUT) * YL + y) * XL + (size_t)x4 * 4;
    const size_t cstride = (size_t)YL * XL;

    const float4 zero = make_float4(0.f, 0.f, 0.f, 0.f);
#pragma unroll 4
    for (int c4 = 0; c4 < COUT / 4; c4++) {
        float4 r0 = zero, r1 = zero, r2 = zero, r3 = zero;
        if (pid.x >= 0) r0 = *(const float4*)(pooled + (size_t)pid.x * COUT + c4 * 4);
        if (pid.y >= 0) r1 = *(const float4*)(pooled + (size_t)pid.y * COUT + c4 * 4);
        if (pid.z >= 0) r2 = *(const float4*)(pooled + (size_t)pid.z * COUT + c4 * 4);
        if (pid.w >= 0) r3 = *(const float4*)(pooled + (size_t)pid.w * COUT + c4 * 4);
        float* o0 = out + obase + (size_t)(c4 * 4) * cstride;
        *(float4*)(o0)               = make_float4(r0.x, r1.x, r2.x, r3.x);
        *(float4*)(o0 + cstride)     = make_float4(r0.y, r1.y, r2.y, r3.y);
        *(float4*)(o0 + 2 * cstride) = make_float4(r0.z, r1.z, r2.z, r3.z);
        *(float4*)(o0 + 3 * cstride) = make_float4(r0.w, r1.w, r2.w, r3.w);
    }
}

// ---------------------------------------------------------------------------
extern "C" void kernel_launch(void* const* d_in, const int* in_sizes, int n_in,
                              void* d_out, int out_size, void* d_ws, size_t ws_size,
                              hipStream_t stream) {
    const float4* pillars = (const float4*)d_in[0];
    const int* coors = (const int*)d_in[1];
    const int* npp = (const int*)d_in[2];
    const float* W = (const float*)d_in[3];
    const float* gamma = (const float*)d_in[4];
    const float* beta = (const float*)d_in[5];
    float* out = (float*)d_out;

    char* ws = (char*)d_ws;
    int* map = (int*)(ws);
    float* stats = (float*)(ws + STATS_OFF);
    float* scale = (float*)(ws + SCALE_OFF);
    float* shift = (float*)(ws + SHIFT_OFF);
    float* pooled = (float*)(ws + POOLED_OFF);

    k_init<<<(MAP_ELEMS + 255) / 256, 256, 0, stream>>>(map, stats);
    k_stats<<<(P_TOT + 255) / 256, 256, 0, stream>>>(pillars, coors, npp, map, stats);
    k_finalize<<<1, 64, 0, stream>>>(W, gamma, beta, stats, scale, shift);
    k_pool<<<P_TOT / 4, 256, 0, stream>>>(pillars, coors, npp, W, scale, shift, pooled);
    k_scatter<<<(BATCH * YL * (XL / 4) + 255) / 256, 256, 0, stream>>>(map, pooled, out);
}

// Round 2
// 318.551 us; speedup vs baseline: 1.7765x; 1.7765x over previous
//
#include <hip/hip_runtime.h>
#include <math.h>

#define P_TOT 40000
#define NMAX 32
#define BATCH 4
#define YL 496
#define XL 432
#define CIN 9
#define COUT 64
#define NTRI 45
#define PN_F 1280000.0f

#define MAP_ELEMS (BATCH * YL * XL)          // 857088
#define MAP_BYTES (MAP_ELEMS * 4)            // 3428352
#define STATS_OFF MAP_BYTES                  // 54 floats (reserve 256B)
#define SCALE_OFF (STATS_OFF + 256)
#define SHIFT_OFF (SCALE_OFF + 256)
#define POOLED_OFF (SHIFT_OFF + 256)

#define STATS_BLOCKS 256

// ---------------------------------------------------------------------------
// K0: init map to -1, zero stat accumulators (ws is poisoned 0xAA each call)
// ---------------------------------------------------------------------------
__global__ __launch_bounds__(256) void k_init(int* __restrict__ map,
                                              float* __restrict__ stats) {
    int i = blockIdx.x * 256 + threadIdx.x;
    if (i < MAP_ELEMS) map[i] = -1;
    if (i < 54) stats[i] = 0.0f;
}

// ---------------------------------------------------------------------------
// K1: moments of the 9 features over all (pillar, point).
//     Half-wave per pillar: lane = (pair_half, point). One coalesced 1KB
//     load per wave-iteration; 54 register accumulators; shuffle reduce +
//     LDS block reduce + 54 atomics per block. Also scatters pillar id->map.
// ---------------------------------------------------------------------------
__global__ __launch_bounds__(256) void k_stats(const float4* __restrict__ pillars,
                                               const int* __restrict__ coors,
                                               const int* __restrict__ npp,
                                               int* __restrict__ map,
                                               float* __restrict__ stats) {
    const int wave = threadIdx.x >> 6;
    const int lane = threadIdx.x & 63;
    const int half = lane >> 5;      // which pillar of the pair
    const int n = lane & 31;         // point index
    const int gw = blockIdx.x * 4 + wave;
    const int totalWaves = STATS_BLOCKS * 4;

    float s1[CIN];
    float s2[NTRI];
#pragma unroll
    for (int i = 0; i < CIN; i++) s1[i] = 0.0f;
#pragma unroll
    for (int i = 0; i < NTRI; i++) s2[i] = 0.0f;

    for (int p0 = gw * 2; p0 < P_TOT; p0 += totalWaves * 2) {
        int p = p0 + half;
        float4 q = pillars[(size_t)p * NMAX + n];   // wave: 64 consecutive float4s

        // center: sum xyz over ALL 32 points of this pillar / npts
        float sx = q.x, sy = q.y, sz = q.z;
#pragma unroll
        for (int off = 1; off < 32; off <<= 1) {
            sx += __shfl_xor(sx, off, 32);
            sy += __shfl_xor(sy, off, 32);
            sz += __shfl_xor(sz, off, 32);
        }
        int npts = npp[p];
        float fn = (float)npts;
        float mx = sx / fn, my = sy / fn, mz = sz / fn;

        int xi = coors[p * 3 + 1];
        int yi = coors[p * 3 + 2];
        if (n == 0) {
            int b = coors[p * 3 + 0];
            map[(b * YL + yi) * XL + xi] = p;
        }
        float cx = (float)xi * 0.16f + 0.08f;
        float cy = (float)yi * 0.16f + (-39.6f);

        float msk = (n < npts) ? 1.0f : 0.0f;
        float f[CIN];
        f[0] = q.x * msk; f[1] = q.y * msk; f[2] = q.z * msk; f[3] = q.w * msk;
        f[4] = (q.x - mx) * msk; f[5] = (q.y - my) * msk; f[6] = (q.z - mz) * msk;
        f[7] = (q.x - cx) * msk; f[8] = (q.y - cy) * msk;

        int k = 0;
#pragma unroll
        for (int a = 0; a < CIN; a++) {
            s1[a] += f[a];
#pragma unroll
            for (int c = a; c < CIN; c++) s2[k++] += f[a] * f[c];
        }
    }

    // full-wave butterfly reduce of the 54 values (once per wave)
#pragma unroll
    for (int i = 0; i < CIN; i++) {
        float v = s1[i];
        for (int off = 1; off < 64; off <<= 1) v += __shfl_xor(v, off, 64);
        s1[i] = v;
    }
#pragma unroll
    for (int i = 0; i < NTRI; i++) {
        float v = s2[i];
        for (int off = 1; off < 64; off <<= 1) v += __shfl_xor(v, off, 64);
        s2[i] = v;
    }

    __shared__ float red[4][54];
    if (lane == 0) {
#pragma unroll
        for (int i = 0; i < CIN; i++) red[wave][i] = s1[i];
#pragma unroll
        for (int i = 0; i < NTRI; i++) red[wave][CIN + i] = s2[i];
    }
    __syncthreads();
    if (threadIdx.x < 54) {
        float v = red[0][threadIdx.x] + red[1][threadIdx.x] +
                  red[2][threadIdx.x] + red[3][threadIdx.x];
        atomicAdd(&stats[threadIdx.x], v);
    }
}

// ---------------------------------------------------------------------------
// K2: derive per-channel BN scale/shift from moment matrix (64 threads)
//     mean_o = W[o].m ; E[x^2]_o = W[o] M W[o]^T ; var = E[x^2] - mean^2
// ---------------------------------------------------------------------------
__global__ void k_finalize(const float* __restrict__ W,
                           const float* __restrict__ gamma,
                           const float* __restrict__ beta,
                           const float* __restrict__ stats,
                           float* __restrict__ scale,
                           float* __restrict__ shift) {
    int o = threadIdx.x;  // 64 threads
    float w[CIN];
#pragma unroll
    for (int c = 0; c < CIN; c++) w[c] = W[o * CIN + c];

    const float invPN = 1.0f / PN_F;
    float mu = 0.0f;
#pragma unroll
    for (int c = 0; c < CIN; c++) mu += w[c] * (stats[c] * invPN);

    float ex2 = 0.0f;
    int k = 0;
#pragma unroll
    for (int a = 0; a < CIN; a++) {
#pragma unroll
        for (int c = a; c < CIN; c++) {
            float Mv = stats[CIN + k] * invPN;
            float t = w[a] * w[c] * Mv;
            ex2 += (a == c) ? t : 2.0f * t;
            k++;
        }
    }
    float var = ex2 - mu * mu;
    float sc = gamma[o] * rsqrtf(var + 1e-3f);
    scale[o] = sc;
    shift[o] = beta[o] - mu * sc;
}

// ---------------------------------------------------------------------------
// K3: pooled[p][o] = relu( max_n ( scale_o * (W[o].f[p][n]) + shift_o ) )
//     wave-per-pillar; features staged in LDS; lane = output channel.
//     Masked columns (f=0) correctly contribute relu(shift_o) to the max.
// ---------------------------------------------------------------------------
__global__ __launch_bounds__(256) void k_pool(const float4* __restrict__ pillars,
                                              const int* __restrict__ coors,
                                              const int* __restrict__ npp,
                                              const float* __restrict__ W,
                                              const float* __restrict__ scale,
                                              const float* __restrict__ shift,
                                              float* __restrict__ pooled) {
    __shared__ float fsh[4][NMAX][CIN];
    int w = threadIdx.x >> 6;
    int lane = threadIdx.x & 63;
    int p = blockIdx.x * 4 + w;
    int n = lane & 31;

    float4 q = pillars[(size_t)p * NMAX + n];
    // sum xyz over the 32 points (both 32-lane halves hold identical copies)
    float sx = q.x, sy = q.y, sz = q.z;
#pragma unroll
    for (int off = 1; off < 32; off <<= 1) {
        sx += __shfl_xor(sx, off, 32);
        sy += __shfl_xor(sy, off, 32);
        sz += __shfl_xor(sz, off, 32);
    }
    int npts = npp[p];
    float fn = (float)npts;
    float mx = sx / fn, my = sy / fn, mz = sz / fn;
    int xi = coors[p * 3 + 1];
    int yi = coors[p * 3 + 2];
    float cx = (float)xi * 0.16f + 0.08f;
    float cy = (float)yi * 0.16f + (-39.6f);

    if (lane < 32) {
        bool valid = (n < npts);
        fsh[w][n][0] = valid ? q.x : 0.0f;
        fsh[w][n][1] = valid ? q.y : 0.0f;
        fsh[w][n][2] = valid ? q.z : 0.0f;
        fsh[w][n][3] = valid ? q.w : 0.0f;
        fsh[w][n][4] = valid ? (q.x - mx) : 0.0f;
        fsh[w][n][5] = valid ? (q.y - my) : 0.0f;
        fsh[w][n][6] = valid ? (q.z - mz) : 0.0f;
        fsh[w][n][7] = valid ? (q.x - cx) : 0.0f;
        fsh[w][n][8] = valid ? (q.y - cy) : 0.0f;
    }
    __syncthreads();

    float wv[CIN];
#pragma unroll
    for (int c = 0; c < CIN; c++) wv[c] = W[lane * CIN + c];
    float sc = scale[lane];
    float sh = shift[lane];

    float m = -INFINITY;
#pragma unroll 4
    for (int nn = 0; nn < NMAX; nn++) {
        float d = 0.0f;
#pragma unroll
        for (int c = 0; c < CIN; c++) d += wv[c] * fsh[w][nn][c];
        m = fmaxf(m, sc * d + sh);
    }
    pooled[(size_t)p * COUT + lane] = fmaxf(m, 0.0f);
}

// ---------------------------------------------------------------------------
// K4: write the whole canvas (B,C,Y,X) coalesced. Thread per (b,y,x4):
//     read int4 map once, loop 64 channels, 4x4 register transpose,
//     float4 stores. Map read traffic 3.4MB, pooled ~10MB, writes 219MB.
// ---------------------------------------------------------------------------
__global__ __launch_bounds__(256) void k_scatter(const int* __restrict__ map,
                                                 const float* __restrict__ pooled,
                                                 float* __restrict__ out) {
    int i = blockIdx.x * 256 + threadIdx.x;  // over BATCH*YL*(XL/4) = 214272
    if (i >= BATCH * YL * (XL / 4)) return;
    int x4 = i % (XL / 4);
    int r = i / (XL / 4);
    int y = r % YL;
    int b = r / YL;

    const int4 pid = *(const int4*)(map + (size_t)(b * YL + y) * XL + x4 * 4);
    size_t obase = ((size_t)(b * COUT) * YL + y) * XL + (size_t)x4 * 4;
    const size_t cstride = (size_t)YL * XL;

    const float4 zero = make_float4(0.f, 0.f, 0.f, 0.f);
#pragma unroll 4
    for (int c4 = 0; c4 < COUT / 4; c4++) {
        float4 r0 = zero, r1 = zero, r2 = zero, r3 = zero;
        if (pid.x >= 0) r0 = *(const float4*)(pooled + (size_t)pid.x * COUT + c4 * 4);
        if (pid.y >= 0) r1 = *(const float4*)(pooled + (size_t)pid.y * COUT + c4 * 4);
        if (pid.z >= 0) r2 = *(const float4*)(pooled + (size_t)pid.z * COUT + c4 * 4);
        if (pid.w >= 0) r3 = *(const float4*)(pooled + (size_t)pid.w * COUT + c4 * 4);
        float* o0 = out + obase + (size_t)(c4 * 4) * cstride;
        *(float4*)(o0)               = make_float4(r0.x, r1.x, r2.x, r3.x);
        *(float4*)(o0 + cstride)     = make_float4(r0.y, r1.y, r2.y, r3.y);
        *(float4*)(o0 + 2 * cstride) = make_float4(r0.z, r1.z, r2.z, r3.z);
        *(float4*)(o0 + 3 * cstride) = make_float4(r0.w, r1.w, r2.w, r3.w);
    }
}

// ---------------------------------------------------------------------------
extern "C" void kernel_launch(void* const* d_in, const int* in_sizes, int n_in,
                              void* d_out, int out_size, void* d_ws, size_t ws_size,
                              hipStream_t stream) {
    const float4* pillars = (const float4*)d_in[0];
    const int* coors = (const int*)d_in[1];
    const int* npp = (const int*)d_in[2];
    const float* W = (const float*)d_in[3];
    const float* gamma = (const float*)d_in[4];
    const float* beta = (const float*)d_in[5];
    float* out = (float*)d_out;

    char* ws = (char*)d_ws;
    int* map = (int*)(ws);
    float* stats = (float*)(ws + STATS_OFF);
    float* scale = (float*)(ws + SCALE_OFF);
    float* shift = (float*)(ws + SHIFT_OFF);
    float* pooled = (float*)(ws + POOLED_OFF);

    k_init<<<(MAP_ELEMS + 255) / 256, 256, 0, stream>>>(map, stats);
    k_stats<<<STATS_BLOCKS, 256, 0, stream>>>(pillars, coors, npp, map, stats);
    k_finalize<<<1, 64, 0, stream>>>(W, gamma, beta, stats, scale, shift);
    k_pool<<<P_TOT / 4, 256, 0, stream>>>(pillars, coors, npp, W, scale, shift, pooled);
    k_scatter<<<(BATCH * YL * (XL / 4) + 255) / 256, 256, 0, stream>>>(map, pooled, out);
}